// Round 3
// baseline (1315.924 us; speedup 1.0000x reference)
//
#include <hip/hip_runtime.h>

#define NB 32768
#define DIN 256
#define NH 4096
#define NDOUT 256

#define BM 64
#define BN 64
#define KB 64
#define PITCH 68   // floats; 272 B row pitch: 16B-aligned, bank-step 4 -> <=2-way conflicts (free)

// ---------- numpy-pairwise-exact row sum-of-squares (n=256) ----------
// Replicates numpy pairwise_sum bit-exactly: two 128-blocks; each block uses 8
// accumulators r[j] = sum_t fl(a[8t+j]^2) (t ascending, adds rounded, products
// rounded separately -> __fmul_rn/__fadd_rn, no contraction), combined as
// ((r0+r1)+(r2+r3))+((r4+r5)+(r6+r7)); block halves added last.
// 8 lanes per row; width-8 xor-shuffle tree == numpy's combine tree bitwise.
__global__ __launch_bounds__(256) void rowsumsq_kernel(const float* __restrict__ A,
                                                       float* __restrict__ out, int nrows) {
    int idx = blockIdx.x * 256 + threadIdx.x;
    int row = idx >> 3;
    int j   = idx & 7;
    if (row >= nrows) return;
    const float* a = A + (size_t)row * DIN;

    float v  = a[j];
    float rA = __fmul_rn(v, v);
#pragma unroll
    for (int t = 1; t < 16; ++t) { v = a[8 * t + j];       rA = __fadd_rn(rA, __fmul_rn(v, v)); }
    v = a[128 + j];
    float rB = __fmul_rn(v, v);
#pragma unroll
    for (int t = 1; t < 16; ++t) { v = a[128 + 8 * t + j]; rB = __fadd_rn(rB, __fmul_rn(v, v)); }

#pragma unroll
    for (int m = 1; m < 8; m <<= 1) {
        rA = __fadd_rn(rA, __shfl_xor(rA, m, 8));
        rB = __fadd_rn(rB, __shfl_xor(rB, m, 8));
    }
    if (j == 0) out[row] = __fadd_rn(rA, rB);
}

// ---------- Gt[h][d] = G[d][h] ----------
__global__ __launch_bounds__(256) void transpose_kernel(const float* __restrict__ G, float* __restrict__ Gt) {
    __shared__ float tile[32][33];
    int bh = blockIdx.x;              // NH/32 = 128
    int bd = blockIdx.y;              // NDOUT/32 = 8
    int tx = threadIdx.x & 31, ty = threadIdx.x >> 5;  // ty 0..7
#pragma unroll
    for (int u = 0; u < 4; ++u) {
        int r = ty + u * 8;
        tile[r][tx] = G[(size_t)(bd * 32 + r) * NH + bh * 32 + tx];
    }
    __syncthreads();
#pragma unroll
    for (int u = 0; u < 4; ++u) {
        int r = ty + u * 8;
        Gt[(size_t)(bh * 32 + r) * NDOUT + bd * 32 + tx] = tile[tx][r];
    }
}

// ---------- per-row argmin of fl(fl(x2 - 2*m) + w2)  (reference-exact) ----------
__global__ __launch_bounds__(256) void argmin_kernel(const float* __restrict__ X, const float* __restrict__ W,
                                                     const float* __restrict__ x2, const float* __restrict__ w2,
                                                     int* __restrict__ winners) {
    __shared__ float Xs[BM * PITCH];
    __shared__ float Ws[BN * PITCH];
    const int tid = threadIdx.x;
    const int tx = tid & 15, ty = tid >> 4;  // micro-tile lane coords
    const int b0 = blockIdx.x * BM;
    const int sr = tid >> 2;                 // staging row 0..63
    const int sq = tid & 3;                  // staging quarter

    float bestV[4];
    int   bestI[4];
    float x2r[4];
#pragma unroll
    for (int i = 0; i < 4; ++i) {
        bestV[i] = 1e30f; bestI[i] = 0;
        x2r[i] = x2[b0 + ty + 16 * i];
    }

    const float4* Xg = reinterpret_cast<const float4*>(X + (size_t)(b0 + sr) * DIN);

    for (int h0 = 0; h0 < NH; h0 += BN) {
        float acc[4][4];
#pragma unroll
        for (int i = 0; i < 4; ++i)
#pragma unroll
            for (int j = 0; j < 4; ++j) acc[i][j] = 0.f;

        const float4* Wg = reinterpret_cast<const float4*>(W + (size_t)(h0 + sr) * DIN);

        // sequential-k fmaf chain (k = 0..255 ascending) == BLAS sgemm
        // single-accumulator FMA microkernel, bitwise.
        for (int kc = 0; kc < DIN; kc += KB) {
            __syncthreads();
#pragma unroll
            for (int u = 0; u < 4; ++u) {
                int kf4 = sq + 4 * u;  // float4 index within KB window (0..15)
                float4 xv = Xg[(kc >> 2) + kf4];
                float4 wv = Wg[(kc >> 2) + kf4];
                *reinterpret_cast<float4*>(&Xs[sr * PITCH + kf4 * 4]) = xv;
                *reinterpret_cast<float4*>(&Ws[sr * PITCH + kf4 * 4]) = wv;
            }
            __syncthreads();
#pragma unroll
            for (int k = 0; k < KB; k += 4) {
                float4 xv[4], wv[4];
#pragma unroll
                for (int i = 0; i < 4; ++i)
                    xv[i] = *reinterpret_cast<const float4*>(&Xs[(ty + 16 * i) * PITCH + k]);
#pragma unroll
                for (int j = 0; j < 4; ++j)
                    wv[j] = *reinterpret_cast<const float4*>(&Ws[(tx + 16 * j) * PITCH + k]);
#pragma unroll
                for (int i = 0; i < 4; ++i)
#pragma unroll
                    for (int j = 0; j < 4; ++j) {
                        acc[i][j] = fmaf(xv[i].x, wv[j].x, acc[i][j]);
                        acc[i][j] = fmaf(xv[i].y, wv[j].y, acc[i][j]);
                        acc[i][j] = fmaf(xv[i].z, wv[j].z, acc[i][j]);
                        acc[i][j] = fmaf(xv[i].w, wv[j].w, acc[i][j]);
                    }
            }
        }
        // epilogue, reference rounding order: t = fl(x2 - 2m) (2m exact), d = fl(t + w2)
#pragma unroll
        for (int j = 0; j < 4; ++j) {
            int c = h0 + tx + 16 * j;
            float wc = w2[c];
#pragma unroll
            for (int i = 0; i < 4; ++i) {
                float t = fmaf(-2.f, acc[i][j], x2r[i]);  // single rounding of exact x2-2m
                float d = __fadd_rn(t, wc);               // second rounding, no contraction
                if (d < bestV[i]) { bestV[i] = d; bestI[i] = c; }  // first-occurrence min
            }
        }
    }

    // reduce across the 16 lanes (tx) sharing each row; tie -> lowest index
#pragma unroll
    for (int i = 0; i < 4; ++i) {
#pragma unroll
        for (int m = 1; m < 16; m <<= 1) {
            float ov = __shfl_xor(bestV[i], m, 16);
            int   oi = __shfl_xor(bestI[i], m, 16);
            if (ov < bestV[i] || (ov == bestV[i] && oi < bestI[i])) { bestV[i] = ov; bestI[i] = oi; }
        }
        if (tx == 0) winners[b0 + ty + 16 * i] = bestI[i];
    }
}

// ---------- gather output rows + winner indices ----------
__global__ __launch_bounds__(256) void gather_kernel(const float* __restrict__ Gt, const int* __restrict__ winners,
                                                     float* __restrict__ out) {
    int b = blockIdx.x;
    int w = winners[b];
    out[(size_t)b * NDOUT + threadIdx.x] = Gt[(size_t)w * NDOUT + threadIdx.x];
    if (threadIdx.x == 0) out[(size_t)NB * NDOUT + b] = (float)w;
}

extern "C" void kernel_launch(void* const* d_in, const int* in_sizes, int n_in,
                              void* d_out, int out_size, void* d_ws, size_t ws_size,
                              hipStream_t stream) {
    const float* x  = (const float*)d_in[0];
    const float* Wk = (const float*)d_in[1];
    const float* Gw = (const float*)d_in[2];
    float* out = (float*)d_out;

    char* ws = (char*)d_ws;
    float* w2      = (float*)ws;                                  // 4096 f   (16 KB)
    float* x2      = (float*)(ws + 16384);                        // 32768 f  (128 KB)
    int*   winners = (int*)(ws + 16384 + 131072);                 // 32768 i  (128 KB)
    float* Gt      = (float*)(ws + 16384 + 131072 + 131072);      // 4 MB

    hipLaunchKernelGGL(rowsumsq_kernel,  dim3((NH * 8) / 256),      dim3(256), 0, stream, Wk, w2, NH);
    hipLaunchKernelGGL(rowsumsq_kernel,  dim3((NB * 8) / 256),      dim3(256), 0, stream, x, x2, NB);
    hipLaunchKernelGGL(transpose_kernel, dim3(NH / 32, NDOUT / 32), dim3(256), 0, stream, Gw, Gt);
    hipLaunchKernelGGL(argmin_kernel,    dim3(NB / BM),             dim3(256), 0, stream, x, Wk, x2, w2, winners);
    hipLaunchKernelGGL(gather_kernel,    dim3(NB),                  dim3(256), 0, stream, Gt, winners, out);
}